// Round 10
// baseline (117.573 us; speedup 1.0000x reference)
//
#include <hip/hip_runtime.h>
#include <hip/hip_bf16.h>
#include <math.h>
#include <string.h>

#define NPTS 524288
#define KC 32
#define DIM 64
#define NTILES 4096        // NPTS / 128 points per block-tile
#define PROW 4128          // partial row: 32 dem + 32*128 rx
#define GRIDX 768          // 3 blocks/CU exactly; 5-6 tiles/block, balanced per CU

typedef __attribute__((ext_vector_type(8)))  short short8v;
typedef __attribute__((ext_vector_type(16))) float f32x16;

// LDS byte map (per block), total 49280 B -> 3 blocks/CU:
//   xt  @0      [128 pt][256B]  byte = pt*256  + (colB ^ ((pt&15)<<4))    (bf16 x | x^2)
//   rl  @32768  [32 comp][256B] byte = comp*256 + (colB ^ ((comp&15)<<4)) (bf16 r, col=pt*2)
//   Wl  @40960  [32 comp][256B] same swizzle as xt
//   cl  @49152  float[32]
#define RL_BASE  32768
#define WL_BASE  40960
#define CL_BASE  49152
#define SMEM_BYTES 49280

__device__ __forceinline__ short f2bf(float f) {              // RNE (prep only)
    unsigned u = __float_as_uint(f);
    unsigned r = (u + 0x7FFFu + ((u >> 16) & 1u)) >> 16;
    return (short)r;
}
__device__ __forceinline__ unsigned short s2bf(float a) {
    __hip_bfloat16 h = __float2bfloat16(a);
    unsigned short u;
    memcpy(&u, &h, 2);
    return u;
}
__device__ __forceinline__ unsigned pk2bf(float a, float b) { // -> v_cvt_pk_bf16_f32
    return (unsigned)s2bf(a) | ((unsigned)s2bf(b) << 16);
}

__global__ void gmm_prep(const float* __restrict__ mu, const float* __restrict__ var,
                         const float* __restrict__ pi, short* __restrict__ W,
                         float* __restrict__ C) {
    int t = threadIdx.x + blockIdx.x * blockDim.x;
    if (t < KC * 128) {
        int k = t >> 7, d = t & 127;
        float iv = 1.0f / var[k * DIM + (d & 63)];
        float v = (d < DIM) ? mu[k * DIM + d] * iv : -0.5f * iv;
        W[t] = f2bf(v);
    }
    if (t < KC) {
        const float LOG2PI = 1.8378770664093453f;
        float s = 0.0f;
        for (int d = 0; d < DIM; ++d) {
            float v = var[t * DIM + d];
            float m = mu[t * DIM + d];
            s += m * m / v + logf(v);
        }
        C[t] = logf(pi[t]) - 0.5f * (s + DIM * LOG2PI);
    }
}

__device__ __forceinline__ void stage_chunk(unsigned char* smem, int w, int c, float4 v, int l) {
    int pt   = w * 32 + c * 4 + (l >> 4);
    int colB = (l & 15) * 8;
    int swz  = (pt & 15) << 4;
    uint2 bx, bx2;
    bx.x  = pk2bf(v.x, v.y);              bx.y  = pk2bf(v.z, v.w);
    bx2.x = pk2bf(v.x * v.x, v.y * v.y);  bx2.y = pk2bf(v.z * v.z, v.w * v.w);
    *(uint2*)(smem + pt * 256 + (colB ^ swz))         = bx;
    *(uint2*)(smem + pt * 256 + ((128 + colB) ^ swz)) = bx2;
}

__global__ __launch_bounds__(256, 3)
void gmm_main(const float* __restrict__ X, const short* __restrict__ W,
              const float* __restrict__ C, float* __restrict__ partials, int g) {
    __shared__ unsigned char smem[SMEM_BYTES];

    const int tid = threadIdx.x;
    const int l   = tid & 63;
    const int w   = tid >> 6;
    const int lm  = l & 31;
    const int lh  = l >> 5;

    // ---- W -> LDS (swizzled); C -> LDS ----
    {
        const uint4* W16 = (const uint4*)W;
#pragma unroll
        for (int i = 0; i < 2; ++i) {
            int idx  = tid * 2 + i;
            int row  = idx >> 4, slot = idx & 15;
            *(uint4*)(smem + WL_BASE + row * 256 + ((slot * 16) ^ ((row & 15) << 4))) = W16[idx];
        }
    }
    if (tid < KC) ((float*)(smem + CL_BASE))[tid] = C[tid];

    short8v onesf;                 // bf16 1.0 fragment for dem-MFMA
#pragma unroll
    for (int j = 0; j < 8; ++j) onesf[j] = (short)0x3F80;

    f32x16 rxacc, demA;
#pragma unroll
    for (int i = 0; i < 16; ++i) { rxacc[i] = 0.0f; demA[i] = 0.0f; }

    const float4* X4 = (const float4*)X;
    const int mypt = w * 32 + lm;

    // prologue loads for tile 0 (in flight across the setup barrier)
    float4 xr[8];
    {
        const float4* xs = X4 + (size_t)blockIdx.x * 2048 + w * 512;
#pragma unroll
        for (int c = 0; c < 8; ++c) xr[c] = xs[c * 64 + l];
    }

    __syncthreads();   // Wl + cl ready

    const float* cl = (const float*)(smem + CL_BASE);

    for (int tile = blockIdx.x; tile < NTILES; tile += g) {
        // ---- stage this wave's 32 rows from prefetched regs (wave-private) ----
#pragma unroll
        for (int c = 0; c < 8; ++c) stage_chunk(smem, w, c, xr[c], l);

        // ---- GEMM-1: S[comp][pt] = sum_d2 W[comp][d2] * xt[pt][d2] ----
        f32x16 s;
#pragma unroll
        for (int r = 0; r < 16; ++r) s[r] = 0.0f;
#pragma unroll
        for (int ks = 0; ks < 8; ++ks) {
            short8v a = *(const short8v*)(smem + WL_BASE + lm * 256 +
                                          ((ks * 32 + lh * 16) ^ ((lm & 15) << 4)));
            short8v b = *(const short8v*)(smem + mypt * 256 +
                                          ((ks * 32 + lh * 16) ^ ((lm & 15) << 4)));
            s = __builtin_amdgcn_mfma_f32_32x32x16_bf16(a, b, s, 0, 0, 0);
        }

        // ---- softmax over 32 comps for pt=mypt (lane pair l, l^32) ----
#pragma unroll
        for (int r = 0; r < 16; ++r) s[r] += cl[(r & 3) + 8 * (r >> 2) + 4 * lh];
        float m = s[0];
#pragma unroll
        for (int r = 1; r < 16; ++r) m = fmaxf(m, s[r]);
        m = fmaxf(m, __shfl_xor(m, 32, 64));
        float sum = 0.0f;
#pragma unroll
        for (int r = 0; r < 16; ++r) { s[r] = __expf(s[r] - m); sum += s[r]; }
        sum += __shfl_xor(sum, 32, 64);
        float inv = 1.0f / sum;
#pragma unroll
        for (int r = 0; r < 16; ++r) {
            float rv = s[r] * inv;
            int comp = (r & 3) + 8 * (r >> 2) + 4 * lh;
            *(unsigned short*)(smem + RL_BASE + comp * 256 +
                               ((mypt * 2) ^ ((comp & 15) << 4))) = s2bf(rv);
        }
        __syncthreads();   // barrier-1: xt + rl complete for all 128 pts

        // ---- GEMM-2: wave w owns d2 = mypt; dem via extra MFMA (B = ones) ----
#pragma unroll
        for (int ks = 0; ks < 8; ++ks) {
            short8v af = *(const short8v*)(smem + RL_BASE + lm * 256 +
                                           ((ks * 32 + lh * 16) ^ ((lm & 15) << 4)));
            short8v bv;
#pragma unroll
            for (int j = 0; j < 8; ++j) {
                int pt = ks * 16 + lh * 8 + j;
                bv[j] = *(const short*)(smem + pt * 256 +
                                        ((mypt * 2) ^ ((pt & 15) << 4)));
            }
            rxacc = __builtin_amdgcn_mfma_f32_32x32x16_bf16(af, bv, rxacc, 0, 0, 0);
            demA  = __builtin_amdgcn_mfma_f32_32x32x16_bf16(af, onesf, demA, 0, 0, 0);
        }

        // ---- issue next-tile loads NOW (pinned after GEMM-2 by sched_barrier);
        //      they stay in flight across the raw barrier (no vmcnt drain) ----
        __builtin_amdgcn_sched_barrier(0);
        if (tile + g < NTILES) {
            const float4* xs = X4 + (size_t)(tile + g) * 2048 + w * 512;
#pragma unroll
            for (int c = 0; c < 8; ++c) xr[c] = xs[c * 64 + l];
        }
        __builtin_amdgcn_sched_barrier(0);

        // barrier-2: protect xt/rl for next staging. lgkmcnt(0) only — the
        // in-flight global loads touch VGPRs, not LDS, so no vmcnt drain.
        asm volatile("s_waitcnt lgkmcnt(0)" ::: "memory");
        __builtin_amdgcn_s_barrier();
        __builtin_amdgcn_sched_barrier(0);
    }

    // ---- store partials: waves own disjoint d2 ----
    float* P = partials + (size_t)blockIdx.x * PROW;
#pragma unroll
    for (int r = 0; r < 16; ++r) {
        int comp = (r & 3) + 8 * (r >> 2) + 4 * lh;
        P[32 + comp * 128 + w * 32 + lm] = rxacc[r];
    }
    if (w == 0 && lm == 0) {       // lanes 0 and 32; demA cols all equal
#pragma unroll
        for (int r = 0; r < 16; ++r)
            P[(r & 3) + 8 * (r >> 2) + 4 * lh] = demA[r];
    }
}

__global__ __launch_bounds__(512)
void gmm_reduce(const float* __restrict__ partials, float* __restrict__ out, int nb) {
    __shared__ float red[512 * 4];
    __shared__ float dred[512];
    __shared__ float rxf[128];
    const int k = blockIdx.x;
    const int t = threadIdx.x;
    const int f4i   = t & 31;
    const int chunk = t >> 5;

    float4 s4 = {0.f, 0.f, 0.f, 0.f};
    const int R = nb >> 4;
#pragma unroll 4
    for (int j = 0; j < R; ++j) {
        int b = chunk * R + j;
        float4 v = *((const float4*)(partials + (size_t)b * PROW + 32 + k * 128) + f4i);
        s4.x += v.x; s4.y += v.y; s4.z += v.z; s4.w += v.w;
    }
    float dp = 0.0f;
    for (int b = t; b < nb; b += 512) dp += partials[(size_t)b * PROW + k];

    *(float4*)(red + t * 4) = s4;
    dred[t] = dp;
    __syncthreads();
    for (int off = 256; off >= 1; off >>= 1) {
        if (t < off) dred[t] += dred[t + off];
        __syncthreads();
    }
    if (t < 32) {
        float4 a = {0.f, 0.f, 0.f, 0.f};
#pragma unroll
        for (int c = 0; c < 16; ++c) {
            float4 v = *(const float4*)(red + (c * 32 + t) * 4);
            a.x += v.x; a.y += v.y; a.z += v.z; a.w += v.w;
        }
        *(float4*)(rxf + t * 4) = a;
    }
    __syncthreads();
    float dem = dred[0];
    if (t < 64) {
        float inv = 1.0f / dem;
        float rx  = rxf[t];
        float rx2 = rxf[t + 64];
        float mu  = rx * inv;
        float va  = rx2 * inv - mu * mu;
        out[k * 129 + 1 + t]  = mu;
        out[k * 129 + 65 + t] = va;
        if (t == 0) out[k * 129] = dem * (1.0f / (float)NPTS);
    }
}

extern "C" void kernel_launch(void* const* d_in, const int* in_sizes, int n_in,
                              void* d_out, int out_size, void* d_ws, size_t ws_size,
                              hipStream_t stream) {
    const float* X   = (const float*)d_in[0];
    const float* mu  = (const float*)d_in[1];
    const float* var = (const float*)d_in[2];
    const float* pi  = (const float*)d_in[3];

    short* W        = (short*)d_ws;
    float* C        = (float*)((char*)d_ws + 8192);
    float* partials = (float*)((char*)d_ws + 8320);
    float* out      = (float*)d_out;

    int g = GRIDX;    // halving keeps nb % 16 == 0
    while (g > 96 && (size_t)8320 + (size_t)g * PROW * 4 > ws_size) g >>= 1;

    gmm_prep<<<16, 256, 0, stream>>>(mu, var, pi, W, C);
    gmm_main<<<g, 256, 0, stream>>>(X, W, C, partials, g);
    gmm_reduce<<<KC, 512, 0, stream>>>(partials, out, g);
}

// Round 11
// 45.097 us; speedup vs baseline: 2.6072x; 2.6072x over previous
//
#include <hip/hip_runtime.h>
#include <hip/hip_bf16.h>
#include <math.h>
#include <string.h>

#define NPTS 524288
#define KC 32
#define DIM 64
#define NTILES 4096        // NPTS / 128 points per block-tile
#define PROW 4128          // partial row: 32 dem + 32*128 rx
#define GRIDX 512          // 2 blocks/CU exactly; 8 tiles/block uniform

typedef __attribute__((ext_vector_type(8)))  short short8v;
typedef __attribute__((ext_vector_type(16))) float f32x16;

// LDS byte map (per block), total 49280 B (2 blocks/CU at launch_bounds(256,2)):
//   xt  @0      [128 pt][256B]  byte = pt*256  + (colB ^ ((pt&15)<<4))    (bf16 x | x^2)
//   rl  @32768  [32 comp][256B] byte = comp*256 + (colB ^ ((comp&15)<<4)) (bf16 r, col=pt*2)
//   Wl  @40960  [32 comp][256B] same swizzle as xt
//   cl  @49152  float[32]
#define RL_BASE  32768
#define WL_BASE  40960
#define CL_BASE  49152
#define SMEM_BYTES 49280

__device__ __forceinline__ short f2bf(float f) {              // RNE (prep only)
    unsigned u = __float_as_uint(f);
    unsigned r = (u + 0x7FFFu + ((u >> 16) & 1u)) >> 16;
    return (short)r;
}
__device__ __forceinline__ unsigned short s2bf(float a) {
    __hip_bfloat16 h = __float2bfloat16(a);
    unsigned short u;
    memcpy(&u, &h, 2);
    return u;
}
__device__ __forceinline__ unsigned pk2bf(float a, float b) { // -> v_cvt_pk_bf16_f32
    return (unsigned)s2bf(a) | ((unsigned)s2bf(b) << 16);
}

__global__ void gmm_prep(const float* __restrict__ mu, const float* __restrict__ var,
                         const float* __restrict__ pi, short* __restrict__ W,
                         float* __restrict__ C) {
    int t = threadIdx.x + blockIdx.x * blockDim.x;
    if (t < KC * 128) {
        int k = t >> 7, d = t & 127;
        float iv = 1.0f / var[k * DIM + (d & 63)];
        float v = (d < DIM) ? mu[k * DIM + d] * iv : -0.5f * iv;
        W[t] = f2bf(v);
    }
    if (t < KC) {
        const float LOG2PI = 1.8378770664093453f;
        float s = 0.0f;
        for (int d = 0; d < DIM; ++d) {
            float v = var[t * DIM + d];
            float m = mu[t * DIM + d];
            s += m * m / v + logf(v);
        }
        C[t] = logf(pi[t]) - 0.5f * (s + DIM * LOG2PI);
    }
}

__device__ __forceinline__ void stage_chunk(unsigned char* smem, int w, int c, float4 v, int l) {
    int pt   = w * 32 + c * 4 + (l >> 4);
    int colB = (l & 15) * 8;
    int swz  = (pt & 15) << 4;
    uint2 bx, bx2;
    bx.x  = pk2bf(v.x, v.y);              bx.y  = pk2bf(v.z, v.w);
    bx2.x = pk2bf(v.x * v.x, v.y * v.y);  bx2.y = pk2bf(v.z * v.z, v.w * v.w);
    *(uint2*)(smem + pt * 256 + (colB ^ swz))         = bx;
    *(uint2*)(smem + pt * 256 + ((128 + colB) ^ swz)) = bx2;
}

__global__ __launch_bounds__(256, 2)
void gmm_main(const float* __restrict__ X, const short* __restrict__ W,
              const float* __restrict__ C, float* __restrict__ partials, int g) {
    __shared__ unsigned char smem[SMEM_BYTES];

    const int tid = threadIdx.x;
    const int l   = tid & 63;
    const int w   = tid >> 6;
    const int lm  = l & 31;
    const int lh  = l >> 5;

    // ---- W -> LDS (swizzled); C -> LDS ----
    {
        const uint4* W16 = (const uint4*)W;
#pragma unroll
        for (int i = 0; i < 2; ++i) {
            int idx  = tid * 2 + i;
            int row  = idx >> 4, slot = idx & 15;
            *(uint4*)(smem + WL_BASE + row * 256 + ((slot * 16) ^ ((row & 15) << 4))) = W16[idx];
        }
    }
    if (tid < KC) ((float*)(smem + CL_BASE))[tid] = C[tid];

    short8v onesf;                 // bf16 1.0 fragment for dem-MFMA
#pragma unroll
    for (int j = 0; j < 8; ++j) onesf[j] = (short)0x3F80;

    f32x16 rxacc, demA;
#pragma unroll
    for (int i = 0; i < 16; ++i) { rxacc[i] = 0.0f; demA[i] = 0.0f; }

    const float4* X4 = (const float4*)X;
    const int mypt = w * 32 + lm;

    // prologue loads for tile 0 (in flight across the setup barrier)
    float4 xr[8];
    {
        const float4* xs = X4 + (size_t)blockIdx.x * 2048 + w * 512;
#pragma unroll
        for (int c = 0; c < 8; ++c) xr[c] = xs[c * 64 + l];
    }

    __syncthreads();   // Wl + cl ready

    const float* cl = (const float*)(smem + CL_BASE);

    for (int tile = blockIdx.x; tile < NTILES; tile += g) {
        // ---- stage this wave's 32 rows from prefetched regs (wave-private) ----
#pragma unroll
        for (int c = 0; c < 8; ++c) stage_chunk(smem, w, c, xr[c], l);

        // ---- GEMM-1: S[comp][pt] = sum_d2 W[comp][d2] * xt[pt][d2] ----
        f32x16 s;
#pragma unroll
        for (int r = 0; r < 16; ++r) s[r] = 0.0f;
#pragma unroll
        for (int ks = 0; ks < 8; ++ks) {
            short8v a = *(const short8v*)(smem + WL_BASE + lm * 256 +
                                          ((ks * 32 + lh * 16) ^ ((lm & 15) << 4)));
            short8v b = *(const short8v*)(smem + mypt * 256 +
                                          ((ks * 32 + lh * 16) ^ ((lm & 15) << 4)));
            s = __builtin_amdgcn_mfma_f32_32x32x16_bf16(a, b, s, 0, 0, 0);
        }

        // ---- softmax over 32 comps for pt=mypt (lane pair l, l^32) ----
#pragma unroll
        for (int r = 0; r < 16; ++r) s[r] += cl[(r & 3) + 8 * (r >> 2) + 4 * lh];
        float m = s[0];
#pragma unroll
        for (int r = 1; r < 16; ++r) m = fmaxf(m, s[r]);
        m = fmaxf(m, __shfl_xor(m, 32, 64));
        float sum = 0.0f;
#pragma unroll
        for (int r = 0; r < 16; ++r) { s[r] = __expf(s[r] - m); sum += s[r]; }
        sum += __shfl_xor(sum, 32, 64);
        float inv = 1.0f / sum;
#pragma unroll
        for (int r = 0; r < 16; ++r) {
            float rv = s[r] * inv;
            int comp = (r & 3) + 8 * (r >> 2) + 4 * lh;
            *(unsigned short*)(smem + RL_BASE + comp * 256 +
                               ((mypt * 2) ^ ((comp & 15) << 4))) = s2bf(rv);
        }
        __syncthreads();   // barrier-1: xt + rl complete for all 128 pts

        // ---- prefetch next tile into regs; latency hides under GEMM-2,
        //      vmcnt drain happens at barrier-2 (after ~1200cyc of GEMM-2) ----
        if (tile + g < NTILES) {
            const float4* xs = X4 + (size_t)(tile + g) * 2048 + w * 512;
#pragma unroll
            for (int c = 0; c < 8; ++c) xr[c] = xs[c * 64 + l];
        }

        // ---- GEMM-2: wave w owns d2 = mypt; dem via extra MFMA (B = ones) ----
#pragma unroll
        for (int ks = 0; ks < 8; ++ks) {
            short8v af = *(const short8v*)(smem + RL_BASE + lm * 256 +
                                           ((ks * 32 + lh * 16) ^ ((lm & 15) << 4)));
            short8v bv;
#pragma unroll
            for (int j = 0; j < 8; ++j) {
                int pt = ks * 16 + lh * 8 + j;
                bv[j] = *(const short*)(smem + pt * 256 +
                                        ((mypt * 2) ^ ((pt & 15) << 4)));
            }
            rxacc = __builtin_amdgcn_mfma_f32_32x32x16_bf16(af, bv, rxacc, 0, 0, 0);
            demA  = __builtin_amdgcn_mfma_f32_32x32x16_bf16(af, onesf, demA, 0, 0, 0);
        }
        __syncthreads();   // barrier-2: xt/rl free for next tile
    }

    // ---- store partials: waves own disjoint d2 ----
    float* P = partials + (size_t)blockIdx.x * PROW;
#pragma unroll
    for (int r = 0; r < 16; ++r) {
        int comp = (r & 3) + 8 * (r >> 2) + 4 * lh;
        P[32 + comp * 128 + w * 32 + lm] = rxacc[r];
    }
    if (w == 0 && lm == 0) {       // lanes 0 and 32; demA cols all equal
#pragma unroll
        for (int r = 0; r < 16; ++r)
            P[(r & 3) + 8 * (r >> 2) + 4 * lh] = demA[r];
    }
}

__global__ __launch_bounds__(512)
void gmm_reduce(const float* __restrict__ partials, float* __restrict__ out, int nb) {
    __shared__ float red[512 * 4];
    __shared__ float dred[512];
    __shared__ float rxf[128];
    const int k = blockIdx.x;
    const int t = threadIdx.x;
    const int f4i   = t & 31;
    const int chunk = t >> 5;

    float4 s4 = {0.f, 0.f, 0.f, 0.f};
    const int R = nb >> 4;
#pragma unroll 4
    for (int j = 0; j < R; ++j) {
        int b = chunk * R + j;
        float4 v = *((const float4*)(partials + (size_t)b * PROW + 32 + k * 128) + f4i);
        s4.x += v.x; s4.y += v.y; s4.z += v.z; s4.w += v.w;
    }
    float dp = 0.0f;
    for (int b = t; b < nb; b += 512) dp += partials[(size_t)b * PROW + k];

    *(float4*)(red + t * 4) = s4;
    dred[t] = dp;
    __syncthreads();
    for (int off = 256; off >= 1; off >>= 1) {
        if (t < off) dred[t] += dred[t + off];
        __syncthreads();
    }
    if (t < 32) {
        float4 a = {0.f, 0.f, 0.f, 0.f};
#pragma unroll
        for (int c = 0; c < 16; ++c) {
            float4 v = *(const float4*)(red + (c * 32 + t) * 4);
            a.x += v.x; a.y += v.y; a.z += v.z; a.w += v.w;
        }
        *(float4*)(rxf + t * 4) = a;
    }
    __syncthreads();
    float dem = dred[0];
    if (t < 64) {
        float inv = 1.0f / dem;
        float rx  = rxf[t];
        float rx2 = rxf[t + 64];
        float mu  = rx * inv;
        float va  = rx2 * inv - mu * mu;
        out[k * 129 + 1 + t]  = mu;
        out[k * 129 + 65 + t] = va;
        if (t == 0) out[k * 129] = dem * (1.0f / (float)NPTS);
    }
}

extern "C" void kernel_launch(void* const* d_in, const int* in_sizes, int n_in,
                              void* d_out, int out_size, void* d_ws, size_t ws_size,
                              hipStream_t stream) {
    const float* X   = (const float*)d_in[0];
    const float* mu  = (const float*)d_in[1];
    const float* var = (const float*)d_in[2];
    const float* pi  = (const float*)d_in[3];

    short* W        = (short*)d_ws;
    float* C        = (float*)((char*)d_ws + 8192);
    float* partials = (float*)((char*)d_ws + 8320);
    float* out      = (float*)d_out;

    int g = GRIDX;    // halving keeps nb % 16 == 0
    while (g > 64 && (size_t)8320 + (size_t)g * PROW * 4 > ws_size) g >>= 1;

    gmm_prep<<<16, 256, 0, stream>>>(mu, var, pi, W, C);
    gmm_main<<<g, 256, 0, stream>>>(X, W, C, partials, g);
    gmm_reduce<<<KC, 512, 0, stream>>>(partials, out, g);
}